// Round 9
// baseline (97.555 us; speedup 1.0000x reference)
//
#include <hip/hip_runtime.h>

// AffineExponential: y = expm(t*W) @ x + bias*t,  ljd = diag(W)*t
//
// Round-8: kill the serial per-k LDS round trip (rounds 3-7 all floor at
// ~20us on that structure). expm(tW) = I + sum_k t^k G_k, G_k = W^k/k!:
//  K1 (gpow, 8 blocks): G_k chain, rows [16r,16r+16) per block, f16 MFMA;
//     emits G_k as apply-ready f16 A-fragments into d_ws (320 KB, each
//     fragment 1 KB, lane-l*16B coalesced).
//  K2 (apply, 256 blocks x 2 waves): pure streaming GEMM. Wave h does
//     k in [5h+1, 5h+5]: per k fold t^k into the x B-frag (4 pk_mul),
//     32 coalesced dwordx4 G-loads + 32 MFMAs straight into y C-regs.
//     NO LDS/barrier/transpose in the loop; one end reduction via LDS.
// Precision: G,x in f16 (~2^-11) -> absmax ~0.01-0.03 vs tol 0.139. KT=10
// (||tW||<=~2 -> tail ~5e-5).

#define DD 128
#define KT 10

typedef float    f32x4 __attribute__((ext_vector_type(4)));
typedef _Float16 f16x8 __attribute__((ext_vector_type(8)));

// gws: slot(k,r,kf) = ((k-1)*8 + r)*4 + kf; halves offset slot*512 + l*8;
// element j holds G_k[16r + (l&15)][32kf + 8*(l>>4) + j].

__global__ __launch_bounds__(256, 1)
void gpow_kernel(const float* __restrict__ weight, _Float16* __restrict__ gws)
{
    __shared__ float wlds[DD * DD];        // 64 KB
    __shared__ float gbuf[2][16 * 136];    // ping-pong 16x128 f32, pad 136

    const int tid = threadIdx.x;
    const int w = tid >> 6, l = tid & 63, n = l & 15, q = l >> 4;
    const int r = blockIdx.x;              // rows [16r, 16r+16)

    for (int i = tid; i < DD * DD / 4; i += 256)
        reinterpret_cast<f32x4*>(wlds)[i] = reinterpret_cast<const f32x4*>(weight)[i];
    __syncthreads();

    // B-frags of W (f16): Bf[nt][kf][j] = W[32kf+8q+j][32w+16nt+n]
    f16x8 Bf[2][4];
#pragma unroll
    for (int nt = 0; nt < 2; ++nt)
#pragma unroll
        for (int kf = 0; kf < 4; ++kf)
#pragma unroll
            for (int j = 0; j < 8; ++j)
                Bf[nt][kf][j] = (_Float16)wlds[(32 * kf + 8 * q + j) * DD + 32 * w + 16 * nt + n];

    // A-frags of G_1 = W rows [16r,16r+16): Af[kf][j] = W[16r+n][32kf+8q+j]
    f16x8 Af[4];
#pragma unroll
    for (int kf = 0; kf < 4; ++kf) {
        const float* p = wlds + (size_t)(16 * r + n) * DD + 32 * kf + 8 * q;
#pragma unroll
        for (int j = 0; j < 8; ++j) Af[kf][j] = (_Float16)p[j];
    }
    // store k=1 fragment (wave w stores kf=w; all waves hold identical Af)
    *reinterpret_cast<f16x8*>(gws + (size_t)(((0 * 8 + r) * 4 + w)) * 512 + l * 8) = Af[w];

    int cur = 0;
#pragma unroll 1
    for (int k = 2; k <= KT; ++k) {
        f32x4 C0 = {0.f, 0.f, 0.f, 0.f}, C1 = {0.f, 0.f, 0.f, 0.f};
#pragma unroll
        for (int kf = 0; kf < 4; ++kf) {
            C0 = __builtin_amdgcn_mfma_f32_16x16x32_f16(Af[kf], Bf[0][kf], C0, 0, 0, 0);
            C1 = __builtin_amdgcn_mfma_f32_16x16x32_f16(Af[kf], Bf[1][kf], C1, 0, 0, 0);
        }
        const float inv = 1.0f / (float)k;
        C0 *= inv;
        C1 *= inv;
        // C: col = lane&15 -> global col 32w+16nt+n, row m = q*4+reg
#pragma unroll
        for (int jr = 0; jr < 4; ++jr) {
            gbuf[cur][(4 * q + jr) * 136 + 32 * w + n]      = C0[jr];
            gbuf[cur][(4 * q + jr) * 136 + 32 * w + 16 + n] = C1[jr];
        }
        __syncthreads();
        // rebuild A-frags from gbuf row n (contiguous 32 B per kf)
#pragma unroll
        for (int kf = 0; kf < 4; ++kf) {
            const float* p = &gbuf[cur][n * 136 + 32 * kf + 8 * q];
            const f32x4 a = *reinterpret_cast<const f32x4*>(p);
            const f32x4 b = *reinterpret_cast<const f32x4*>(p + 4);
#pragma unroll
            for (int j = 0; j < 4; ++j) {
                Af[kf][j]     = (_Float16)a[j];
                Af[kf][j + 4] = (_Float16)b[j];
            }
        }
        *reinterpret_cast<f16x8*>(gws + (size_t)((((k - 1) * 8 + r) * 4 + w)) * 512 + l * 8) = Af[w];
        cur ^= 1;
    }
}

__global__ __launch_bounds__(128, 1)
void apply_kernel(const float* __restrict__ x,
                  const float* __restrict__ t,
                  const float* __restrict__ weight,
                  const float* __restrict__ bias,
                  const _Float16* __restrict__ gws,
                  float* __restrict__ out, int B)
{
    __shared__ float pbuf[8 * 64 * 4];     // 8 KB: wave-1 partial y

    const int tid = threadIdx.x;
    const int h = tid >> 6, l = tid & 63, n = l & 15, q = l >> 4;
    const int s0 = blockIdx.x * 16;

    const float tn = t[s0 + n];
    const float* xp = x + (size_t)(s0 + n) * DD;

    // x B-frags (f16, unscaled): xb[kf][j] = x[s0+n][32kf+8q+j]
    f16x8 xb[4];
#pragma unroll
    for (int kf = 0; kf < 4; ++kf) {
        const f32x4 a = *reinterpret_cast<const f32x4*>(xp + 32 * kf + 8 * q);
        const f32x4 b = *reinterpret_cast<const f32x4*>(xp + 32 * kf + 8 * q + 4);
#pragma unroll
        for (int j = 0; j < 4; ++j) {
            xb[kf][j]     = (_Float16)a[j];
            xb[kf][j + 4] = (_Float16)b[j];
        }
    }

    // y accumulators (C-layout); wave0 seeds the k=0 term (= x)
    f32x4 y[8];
#pragma unroll
    for (int r = 0; r < 8; ++r)
        y[r] = (h == 0) ? *reinterpret_cast<const f32x4*>(xp + 16 * r + 4 * q)
                        : (f32x4){0.f, 0.f, 0.f, 0.f};

    float tk = tn;                          // t^(5h+1)
    for (int i = 0; i < 5 * h; ++i) tk *= tn;

#pragma unroll 1
    for (int kk = 0; kk < 5; ++kk) {
        const int k = 5 * h + 1 + kk;
        const _Float16 th = (_Float16)tk;
        f16x8 cv;
#pragma unroll
        for (int j = 0; j < 8; ++j) cv[j] = th;
        f16x8 xk[4];
#pragma unroll
        for (int kf = 0; kf < 4; ++kf) xk[kf] = xb[kf] * cv;

        const _Float16* gk = gws + (size_t)((k - 1) * 8) * 4 * 512 + l * 8;
#pragma unroll 4
        for (int r = 0; r < 8; ++r) {
            f16x8 g0 = *reinterpret_cast<const f16x8*>(gk + (r * 4 + 0) * 512);
            f16x8 g1 = *reinterpret_cast<const f16x8*>(gk + (r * 4 + 1) * 512);
            f16x8 g2 = *reinterpret_cast<const f16x8*>(gk + (r * 4 + 2) * 512);
            f16x8 g3 = *reinterpret_cast<const f16x8*>(gk + (r * 4 + 3) * 512);
            y[r] = __builtin_amdgcn_mfma_f32_16x16x32_f16(g0, xk[0], y[r], 0, 0, 0);
            y[r] = __builtin_amdgcn_mfma_f32_16x16x32_f16(g1, xk[1], y[r], 0, 0, 0);
            y[r] = __builtin_amdgcn_mfma_f32_16x16x32_f16(g2, xk[2], y[r], 0, 0, 0);
            y[r] = __builtin_amdgcn_mfma_f32_16x16x32_f16(g3, xk[3], y[r], 0, 0, 0);
        }
        tk *= tn;
    }

    // ljd = diag(W)*t: thread -> sample tid>>3, dims (tid&7)*16..+16 (coalesced)
    {
        const int s  = tid >> 3;
        const int dg = (tid & 7) * 16;
        const float ts = t[s0 + s];
        float* lp = out + (size_t)B * DD + (size_t)(s0 + s) * DD + dg;
#pragma unroll
        for (int c = 0; c < 4; ++c) {
            f32x4 o;
#pragma unroll
            for (int j = 0; j < 4; ++j)
                o[j] = weight[(size_t)(dg + 4 * c + j) * DD + dg + 4 * c + j] * ts;
            *reinterpret_cast<f32x4*>(lp + 4 * c) = o;
        }
    }

    if (h == 1) {
#pragma unroll
        for (int r = 0; r < 8; ++r)
            *reinterpret_cast<f32x4*>(&pbuf[(r * 64 + l) * 4]) = y[r];
    }
    __syncthreads();
    if (h == 0) {
#pragma unroll
        for (int r = 0; r < 8; ++r) {
            const f32x4 p  = *reinterpret_cast<const f32x4*>(&pbuf[(r * 64 + l) * 4]);
            const f32x4 bv = *reinterpret_cast<const f32x4*>(bias + 16 * r + 4 * q);
            const f32x4 o  = y[r] + p + bv * tn;
            *reinterpret_cast<f32x4*>(out + (size_t)(s0 + n) * DD + 16 * r + 4 * q) = o;
        }
    }
}

extern "C" void kernel_launch(void* const* d_in, const int* in_sizes, int n_in,
                              void* d_out, int out_size, void* d_ws, size_t ws_size,
                              hipStream_t stream) {
    const float* x      = (const float*)d_in[0];
    const float* t      = (const float*)d_in[1];
    const float* weight = (const float*)d_in[2];
    const float* bias   = (const float*)d_in[3];
    float* out = (float*)d_out;
    _Float16* gws = (_Float16*)d_ws;

    const int B = in_sizes[1];             // one scalar t per sample

    gpow_kernel<<<8, 256, 0, stream>>>(weight, gws);
    apply_kernel<<<B / 16, 128, 0, stream>>>(x, t, weight, bias, gws, out, B);
}